// Round 1
// baseline (44993.289 us; speedup 1.0000x reference)
//
#include <hip/hip_runtime.h>
#include <hip/hip_bf16.h>

#define T_ 1024
#define B_ 32
#define H_ 256
#define G3 768   // 3*H

__device__ __forceinline__ float sigmoidf_(float x) { return 1.f / (1.f + __expf(-x)); }
__device__ __forceinline__ float tanhf_(float x) {
    float e = __expf(2.f * x);
    return (e - 1.f) / (e + 1.f);
}

// C[M,N] = A[M,K] @ W[N,K]^T + bias[N]   (A row-major, W row-major: "NT" dot-product GEMM)
// BM=BN=64, BK=16, 256 threads, 4x4 micro-tile per thread.
template <typename CT>
__global__ __launch_bounds__(256) void gemm_bias_nt(
    const float* __restrict__ A, const float* __restrict__ W,
    const float* __restrict__ bias, CT* __restrict__ C,
    int M, int N, int K)
{
    __shared__ float As[16][68];   // [k][m], row stride 68 floats = 272B (16B aligned)
    __shared__ float Ws[16][68];   // [k][n]
    const int tid = threadIdx.x;
    const int bm = blockIdx.y * 64;
    const int bn = blockIdx.x * 64;
    const int lr = tid & 63;       // loader row within tile
    const int lc = tid >> 6;       // loader k-group (0..3) -> k offset lc*4
    const int tx = tid & 15;       // n sub-tile
    const int ty = tid >> 4;       // m sub-tile

    const float* Ap = A + (size_t)(bm + lr) * K + lc * 4;
    const float* Wp = W + (size_t)(bn + lr) * K + lc * 4;

    float acc[4][4];
#pragma unroll
    for (int i = 0; i < 4; ++i)
#pragma unroll
        for (int j = 0; j < 4; ++j) acc[i][j] = 0.f;

    for (int k0 = 0; k0 < K; k0 += 16) {
        float4 av = *(const float4*)(Ap + k0);
        float4 wv = *(const float4*)(Wp + k0);
        __syncthreads();
        As[lc * 4 + 0][lr] = av.x; As[lc * 4 + 1][lr] = av.y;
        As[lc * 4 + 2][lr] = av.z; As[lc * 4 + 3][lr] = av.w;
        Ws[lc * 4 + 0][lr] = wv.x; Ws[lc * 4 + 1][lr] = wv.y;
        Ws[lc * 4 + 2][lr] = wv.z; Ws[lc * 4 + 3][lr] = wv.w;
        __syncthreads();
#pragma unroll
        for (int kk = 0; kk < 16; ++kk) {
            float4 a4 = *(const float4*)&As[kk][ty * 4];
            float4 w4 = *(const float4*)&Ws[kk][tx * 4];
            float am[4] = {a4.x, a4.y, a4.z, a4.w};
            float wn[4] = {w4.x, w4.y, w4.z, w4.w};
#pragma unroll
            for (int i = 0; i < 4; ++i)
#pragma unroll
                for (int j = 0; j < 4; ++j) acc[i][j] += am[i] * wn[j];
        }
    }

#pragma unroll
    for (int i = 0; i < 4; ++i) {
        size_t cbase = (size_t)(bm + ty * 4 + i) * N + bn + tx * 4;
#pragma unroll
        for (int j = 0; j < 4; ++j) {
            float v = acc[i][j] + bias[bn + tx * 4 + j];
            C[cbase + j] = (CT)v;
        }
    }
}

// One workgroup per (batch, direction). 512 threads: thread = (j in 0..255, kh in 0..1),
// kh splits the K=256 dot in half for 8 waves of latency hiding.
// P holds precomputed input projections gi = x @ w_ih^T + b_ih over the UNROLLED sequence;
// backward rolls are handled purely by index: scan step u reads/writes row (u+len) mod T.
template <typename PT>
__global__ __launch_bounds__(512) void gru_scan(
    const PT* __restrict__ Pf, const PT* __restrict__ Pb,
    const float* __restrict__ Wf, const float* __restrict__ Wb,
    const float* __restrict__ bhf, const float* __restrict__ bhb,
    const int* __restrict__ lengths,
    float* __restrict__ out,   // (T,B,512): writes [row][b][dir*256 + j]
    float* __restrict__ hn,    // this layer's 2*B*H slice: [dir][b][j]
    int do_mask)
{
    const int b = blockIdx.x >> 1;
    const int dir = blockIdx.x & 1;
    const PT* P = dir ? Pb : Pf;
    const float* W = dir ? Wb : Wf;
    const float* bh = dir ? bhb : bhf;
    const int len = lengths[b];
    const int hn_step = dir ? (T_ - len) : (len - 1);

    __shared__ float h[H_];
    __shared__ float part[6][H_];   // [gate*2 + kh][j]

    const int tid = threadIdx.x;
    const int j = tid & 255;
    const int kh = tid >> 8;

    if (tid < H_) h[tid] = 0.f;

    float bh0 = 0.f, bh1 = 0.f, bh2 = 0.f;
    if (tid < H_) { bh0 = bh[j]; bh1 = bh[j + 256]; bh2 = bh[j + 512]; }

    const float4* w0 = (const float4*)(W + (size_t)j * H_ + kh * 128);
    const float4* w1 = (const float4*)(W + (size_t)(j + 256) * H_ + kh * 128);
    const float4* w2 = (const float4*)(W + (size_t)(j + 512) * H_ + kh * 128);

    float* outp = out + (size_t)b * 512 + dir * 256;
    float* hnp = hn + (size_t)dir * (B_ * H_) + (size_t)b * H_;

    __syncthreads();

    for (int s = 0; s < T_; ++s) {
        const int u = dir ? (T_ - 1 - s) : s;
        const int row = dir ? ((u + len) & (T_ - 1)) : u;

        // prefetch this step's input-projection gates (consumed after the barrier)
        float ir = 0.f, iz = 0.f, inn = 0.f;
        if (tid < H_) {
            size_t pb = (size_t)row * (B_ * G3) + (size_t)b * G3 + j;
            ir  = (float)P[pb];
            iz  = (float)P[pb + 256];
            inn = (float)P[pb + 512];
        }

        const float4* hv4 = (const float4*)(h + kh * 128);
        float ar = 0.f, az = 0.f, an = 0.f;
#pragma unroll 8
        for (int k = 0; k < 32; ++k) {
            float4 x4 = hv4[k];
            float4 a4 = w0[k];
            float4 b4 = w1[k];
            float4 c4 = w2[k];
            ar += a4.x * x4.x + a4.y * x4.y + a4.z * x4.z + a4.w * x4.w;
            az += b4.x * x4.x + b4.y * x4.y + b4.z * x4.z + b4.w * x4.w;
            an += c4.x * x4.x + c4.y * x4.y + c4.z * x4.z + c4.w * x4.w;
        }
        part[0 + kh][j] = ar;
        part[2 + kh][j] = az;
        part[4 + kh][j] = an;
        __syncthreads();

        if (tid < H_) {
            float gr = part[0][j] + part[1][j] + bh0;
            float gz = part[2][j] + part[3][j] + bh1;
            float gn = part[4][j] + part[5][j] + bh2;
            float r = sigmoidf_(ir + gr);
            float z = sigmoidf_(iz + gz);
            float nn = tanhf_(inn + r * gn);
            float hnew = (1.f - z) * nn + z * h[j];
            h[j] = hnew;
            float ov = (do_mask && row >= len) ? 0.f : hnew;
            outp[(size_t)row * (B_ * 512) + j] = ov;
            if (u == hn_step) hnp[j] = hnew;
        }
        __syncthreads();
    }
}

extern "C" void kernel_launch(void* const* d_in, const int* in_sizes, int n_in,
                              void* d_out, int out_size, void* d_ws, size_t ws_size,
                              hipStream_t stream)
{
    const float* x        = (const float*)d_in[0];
    const float* w_ih_l0f = (const float*)d_in[1];
    const float* w_hh_l0f = (const float*)d_in[2];
    const float* b_ih_l0f = (const float*)d_in[3];
    const float* b_hh_l0f = (const float*)d_in[4];
    const float* w_ih_l0b = (const float*)d_in[5];
    const float* w_hh_l0b = (const float*)d_in[6];
    const float* b_ih_l0b = (const float*)d_in[7];
    const float* b_hh_l0b = (const float*)d_in[8];
    const float* w_ih_l1f = (const float*)d_in[9];
    const float* w_hh_l1f = (const float*)d_in[10];
    const float* b_ih_l1f = (const float*)d_in[11];
    const float* b_hh_l1f = (const float*)d_in[12];
    const float* w_ih_l1b = (const float*)d_in[13];
    const float* w_hh_l1b = (const float*)d_in[14];
    const float* b_ih_l1b = (const float*)d_in[15];
    const float* b_hh_l1b = (const float*)d_in[16];
    const int*   lengths  = (const int*)d_in[17];

    float* out = (float*)d_out;
    const size_t OUT_OFF = (size_t)T_ * B_ * 512;   // start of last_hidden
    float* hn0 = out + OUT_OFF;                     // slots 0,1: h0f, h0b
    float* hn1 = hn0 + 2 * B_ * H_;                 // slots 2,3: h1f, h1b

    const size_t PE = (size_t)T_ * B_ * G3;         // elements per projection buffer
    const int M = T_ * B_;
    dim3 gg(G3 / 64, M / 64);

    if (ws_size >= 2 * PE * sizeof(float)) {
        float* P0 = (float*)d_ws;
        float* P1 = P0 + PE;
        // ---- layer 0 ----
        gemm_bias_nt<float><<<gg, 256, 0, stream>>>(x, w_ih_l0f, b_ih_l0f, P0, M, G3, 256);
        gemm_bias_nt<float><<<gg, 256, 0, stream>>>(x, w_ih_l0b, b_ih_l0b, P1, M, G3, 256);
        // out0 staged in d_out (overwritten later by layer-1 scan)
        gru_scan<float><<<64, 512, 0, stream>>>(P0, P1, w_hh_l0f, w_hh_l0b,
                                                b_hh_l0f, b_hh_l0b, lengths, out, hn0, 0);
        // ---- layer 1 ---- (P0/P1 reused; out0 read from d_out, K=512)
        gemm_bias_nt<float><<<gg, 256, 0, stream>>>(out, w_ih_l1f, b_ih_l1f, P0, M, G3, 512);
        gemm_bias_nt<float><<<gg, 256, 0, stream>>>(out, w_ih_l1b, b_ih_l1b, P1, M, G3, 512);
        gru_scan<float><<<64, 512, 0, stream>>>(P0, P1, w_hh_l1f, w_hh_l1b,
                                                b_hh_l1f, b_hh_l1b, lengths, out, hn1, 1);
    } else if (ws_size >= 2 * PE * sizeof(__hip_bfloat16)) {
        // fallback: projections stored bf16 (half the workspace)
        __hip_bfloat16* P0 = (__hip_bfloat16*)d_ws;
        __hip_bfloat16* P1 = P0 + PE;
        gemm_bias_nt<__hip_bfloat16><<<gg, 256, 0, stream>>>(x, w_ih_l0f, b_ih_l0f, P0, M, G3, 256);
        gemm_bias_nt<__hip_bfloat16><<<gg, 256, 0, stream>>>(x, w_ih_l0b, b_ih_l0b, P1, M, G3, 256);
        gru_scan<__hip_bfloat16><<<64, 512, 0, stream>>>(P0, P1, w_hh_l0f, w_hh_l0b,
                                                         b_hh_l0f, b_hh_l0b, lengths, out, hn0, 0);
        gemm_bias_nt<__hip_bfloat16><<<gg, 256, 0, stream>>>(out, w_ih_l1f, b_ih_l1f, P0, M, G3, 512);
        gemm_bias_nt<__hip_bfloat16><<<gg, 256, 0, stream>>>(out, w_ih_l1b, b_ih_l1b, P1, M, G3, 512);
        gru_scan<__hip_bfloat16><<<64, 512, 0, stream>>>(P0, P1, w_hh_l1f, w_hh_l1b,
                                                         b_hh_l1f, b_hh_l1b, lengths, out, hn1, 1);
    }
    // if ws_size is smaller than even the bf16 path, nothing is launched and the
    // harness will show a clear validation failure (we'd then restructure).
}

// Round 2
// 3689.504 us; speedup vs baseline: 12.1949x; 12.1949x over previous
//
#include <hip/hip_runtime.h>
#include <hip/hip_bf16.h>
#include <hip/hip_fp16.h>

#define T_ 1024
#define B_ 32
#define H_ 256
#define G3 768   // 3*H

typedef _Float16 half2_t __attribute__((ext_vector_type(2)));

__device__ __forceinline__ float sigmoidf_(float x) { return 1.f / (1.f + __expf(-x)); }
__device__ __forceinline__ float tanhf_(float x) {
    float e = __expf(2.f * x);
    return (e - 1.f) / (e + 1.f);
}

__device__ __forceinline__ float fdot2_(unsigned int w, unsigned int h, float acc) {
#if __has_builtin(__builtin_amdgcn_fdot2)
    return __builtin_amdgcn_fdot2(__builtin_bit_cast(half2_t, w),
                                  __builtin_bit_cast(half2_t, h), acc, false);
#else
    half2_t a = __builtin_bit_cast(half2_t, w);
    half2_t b = __builtin_bit_cast(half2_t, h);
    return acc + (float)a[0] * (float)b[0] + (float)a[1] * (float)b[1];
#endif
}

__device__ __forceinline__ unsigned int pack_f16rn(float x, float y) {
    unsigned short ux = __half_as_ushort(__float2half_rn(x));
    unsigned short uy = __half_as_ushort(__float2half_rn(y));
    return (unsigned int)ux | ((unsigned int)uy << 16);
}

// C[M,N] = A[M,K] @ W[N,K]^T + bias[N]
template <typename CT>
__global__ __launch_bounds__(256) void gemm_bias_nt(
    const float* __restrict__ A, const float* __restrict__ W,
    const float* __restrict__ bias, CT* __restrict__ C,
    int M, int N, int K)
{
    __shared__ float As[16][68];
    __shared__ float Ws[16][68];
    const int tid = threadIdx.x;
    const int bm = blockIdx.y * 64;
    const int bn = blockIdx.x * 64;
    const int lr = tid & 63;
    const int lc = tid >> 6;
    const int tx = tid & 15;
    const int ty = tid >> 4;

    const float* Ap = A + (size_t)(bm + lr) * K + lc * 4;
    const float* Wp = W + (size_t)(bn + lr) * K + lc * 4;

    float acc[4][4];
#pragma unroll
    for (int i = 0; i < 4; ++i)
#pragma unroll
        for (int j = 0; j < 4; ++j) acc[i][j] = 0.f;

    for (int k0 = 0; k0 < K; k0 += 16) {
        float4 av = *(const float4*)(Ap + k0);
        float4 wv = *(const float4*)(Wp + k0);
        __syncthreads();
        As[lc * 4 + 0][lr] = av.x; As[lc * 4 + 1][lr] = av.y;
        As[lc * 4 + 2][lr] = av.z; As[lc * 4 + 3][lr] = av.w;
        Ws[lc * 4 + 0][lr] = wv.x; Ws[lc * 4 + 1][lr] = wv.y;
        Ws[lc * 4 + 2][lr] = wv.z; Ws[lc * 4 + 3][lr] = wv.w;
        __syncthreads();
#pragma unroll
        for (int kk = 0; kk < 16; ++kk) {
            float4 a4 = *(const float4*)&As[kk][ty * 4];
            float4 w4 = *(const float4*)&Ws[kk][tx * 4];
            float am[4] = {a4.x, a4.y, a4.z, a4.w};
            float wn[4] = {w4.x, w4.y, w4.z, w4.w};
#pragma unroll
            for (int i = 0; i < 4; ++i)
#pragma unroll
                for (int j = 0; j < 4; ++j) acc[i][j] += am[i] * wn[j];
        }
    }

#pragma unroll
    for (int i = 0; i < 4; ++i) {
        size_t cbase = (size_t)(bm + ty * 4 + i) * N + bn + tx * 4;
#pragma unroll
        for (int j = 0; j < 4; ++j) {
            float v = acc[i][j] + bias[bn + tx * 4 + j];
            C[cbase + j] = (CT)v;
        }
    }
}

// One WG per (batch, direction), 512 threads = (j in 0..255, kh in 0..1).
// W_hh held CU-resident in registers as packed f16x2: thread (j,kh) owns rows
// j, j+256, j+512 over k in [kh*128, kh*128+128). h state: fp32 in thread j's
// register; broadcast to the matvec via a 512B f16 LDS buffer.
template <typename PT>
__global__ __launch_bounds__(512, 2) void gru_scan_reg(
    const PT* __restrict__ Pf, const PT* __restrict__ Pb,
    const float* __restrict__ Wf, const float* __restrict__ Wb,
    const float* __restrict__ bhf, const float* __restrict__ bhb,
    const int* __restrict__ lengths,
    float* __restrict__ out,   // (T,B,512)
    float* __restrict__ hn,    // [dir][b][j]
    int do_mask)
{
    const int b = blockIdx.x >> 1;
    const int dir = blockIdx.x & 1;
    const PT* P = dir ? Pb : Pf;
    const float* W = dir ? Wb : Wf;
    const float* bh = dir ? bhb : bhf;
    const int len = lengths[b];
    const int hn_step = dir ? (T_ - len) : (len - 1);

    __shared__ unsigned short h16s[H_];      // h as f16 for the matvec
    __shared__ float part[6][H_];            // [gate*2 + kh][j]

    const int tid = threadIdx.x;
    const int j = tid & 255;
    const int kh = tid >> 8;

    // ---- load W_hh into registers (one time; uncoalesced but amortized) ----
    unsigned int wr[64], wz[64], wn[64];
    {
        const float4* r0 = (const float4*)(W + (size_t)j * H_ + kh * 128);
        const float4* r1 = (const float4*)(W + (size_t)(j + 256) * H_ + kh * 128);
        const float4* r2 = (const float4*)(W + (size_t)(j + 512) * H_ + kh * 128);
#pragma unroll
        for (int q = 0; q < 32; ++q) {
            float4 a = r0[q]; wr[2 * q] = pack_f16rn(a.x, a.y); wr[2 * q + 1] = pack_f16rn(a.z, a.w);
            float4 c = r1[q]; wz[2 * q] = pack_f16rn(c.x, c.y); wz[2 * q + 1] = pack_f16rn(c.z, c.w);
            float4 d = r2[q]; wn[2 * q] = pack_f16rn(d.x, d.y); wn[2 * q + 1] = pack_f16rn(d.z, d.w);
        }
    }

    float bh0 = 0.f, bh1 = 0.f, bh2 = 0.f;
    if (tid < H_) { bh0 = bh[j]; bh1 = bh[j + 256]; bh2 = bh[j + 512]; }

    float hreg = 0.f;                 // h[j] fp32 state (thread j)
    if (tid < H_) h16s[tid] = 0;      // f16 h buffer

    float* outp = out + (size_t)b * 512 + dir * 256;
    float* hnp = hn + (size_t)dir * (B_ * H_) + (size_t)b * H_;

    // prologue: load P for step 0
    float cir = 0.f, ciz = 0.f, cin = 0.f;
    {
        const int u0 = dir ? (T_ - 1) : 0;
        const int row0 = dir ? ((u0 + len) & (T_ - 1)) : u0;
        if (tid < H_) {
            size_t pb = (size_t)row0 * (B_ * G3) + (size_t)b * G3 + j;
            cir = (float)P[pb]; ciz = (float)P[pb + 256]; cin = (float)P[pb + 512];
        }
    }
    __syncthreads();

    for (int s = 0; s < T_; ++s) {
        const int u = dir ? (T_ - 1 - s) : s;
        const int row = dir ? ((u + len) & (T_ - 1)) : u;

        // prefetch next step's input projections (consumed next iteration)
        float nir = 0.f, niz = 0.f, nin = 0.f;
        if (s + 1 < T_ && tid < H_) {
            const int u2 = dir ? (T_ - 2 - s) : (s + 1);
            const int row2 = dir ? ((u2 + len) & (T_ - 1)) : u2;
            size_t pb = (size_t)row2 * (B_ * G3) + (size_t)b * G3 + j;
            nir = (float)P[pb]; niz = (float)P[pb + 256]; nin = (float)P[pb + 512];
        }

        // ---- matvec from register-resident weights, f16 h broadcast ----
        float ar0 = 0.f, ar1 = 0.f, az0 = 0.f, az1 = 0.f, an0 = 0.f, an1 = 0.f;
        const uint4* hv = ((const uint4*)h16s) + kh * 16;
#pragma unroll
        for (int m = 0; m < 8; ++m) {
            uint4 ua = hv[2 * m];
            uint4 ub = hv[2 * m + 1];
            ar0 = fdot2_(wr[8 * m + 0], ua.x, ar0);
            az0 = fdot2_(wz[8 * m + 0], ua.x, az0);
            an0 = fdot2_(wn[8 * m + 0], ua.x, an0);
            ar1 = fdot2_(wr[8 * m + 1], ua.y, ar1);
            az1 = fdot2_(wz[8 * m + 1], ua.y, az1);
            an1 = fdot2_(wn[8 * m + 1], ua.y, an1);
            ar0 = fdot2_(wr[8 * m + 2], ua.z, ar0);
            az0 = fdot2_(wz[8 * m + 2], ua.z, az0);
            an0 = fdot2_(wn[8 * m + 2], ua.z, an0);
            ar1 = fdot2_(wr[8 * m + 3], ua.w, ar1);
            az1 = fdot2_(wz[8 * m + 3], ua.w, az1);
            an1 = fdot2_(wn[8 * m + 3], ua.w, an1);
            ar0 = fdot2_(wr[8 * m + 4], ub.x, ar0);
            az0 = fdot2_(wz[8 * m + 4], ub.x, az0);
            an0 = fdot2_(wn[8 * m + 4], ub.x, an0);
            ar1 = fdot2_(wr[8 * m + 5], ub.y, ar1);
            az1 = fdot2_(wz[8 * m + 5], ub.y, az1);
            an1 = fdot2_(wn[8 * m + 5], ub.y, an1);
            ar0 = fdot2_(wr[8 * m + 6], ub.z, ar0);
            az0 = fdot2_(wz[8 * m + 6], ub.z, az0);
            an0 = fdot2_(wn[8 * m + 6], ub.z, an0);
            ar1 = fdot2_(wr[8 * m + 7], ub.w, ar1);
            az1 = fdot2_(wz[8 * m + 7], ub.w, az1);
            an1 = fdot2_(wn[8 * m + 7], ub.w, an1);
        }
        part[0 + kh][j] = ar0 + ar1;
        part[2 + kh][j] = az0 + az1;
        part[4 + kh][j] = an0 + an1;
        __syncthreads();

        if (tid < H_) {
            float gr = part[0][j] + part[1][j] + bh0;
            float gz = part[2][j] + part[3][j] + bh1;
            float gn = part[4][j] + part[5][j] + bh2;
            float r = sigmoidf_(cir + gr);
            float z = sigmoidf_(ciz + gz);
            float nn = tanhf_(cin + r * gn);
            float hnew = (1.f - z) * nn + z * hreg;
            hreg = hnew;
            h16s[j] = __half_as_ushort(__float2half_rn(hnew));
            float ov = (do_mask && row >= len) ? 0.f : hnew;
            outp[(size_t)row * (B_ * 512) + j] = ov;
            if (u == hn_step) hnp[j] = hnew;
        }
        __syncthreads();

        cir = nir; ciz = niz; cin = nin;
    }
}

extern "C" void kernel_launch(void* const* d_in, const int* in_sizes, int n_in,
                              void* d_out, int out_size, void* d_ws, size_t ws_size,
                              hipStream_t stream)
{
    const float* x        = (const float*)d_in[0];
    const float* w_ih_l0f = (const float*)d_in[1];
    const float* w_hh_l0f = (const float*)d_in[2];
    const float* b_ih_l0f = (const float*)d_in[3];
    const float* b_hh_l0f = (const float*)d_in[4];
    const float* w_ih_l0b = (const float*)d_in[5];
    const float* w_hh_l0b = (const float*)d_in[6];
    const float* b_ih_l0b = (const float*)d_in[7];
    const float* b_hh_l0b = (const float*)d_in[8];
    const float* w_ih_l1f = (const float*)d_in[9];
    const float* w_hh_l1f = (const float*)d_in[10];
    const float* b_ih_l1f = (const float*)d_in[11];
    const float* b_hh_l1f = (const float*)d_in[12];
    const float* w_ih_l1b = (const float*)d_in[13];
    const float* w_hh_l1b = (const float*)d_in[14];
    const float* b_ih_l1b = (const float*)d_in[15];
    const float* b_hh_l1b = (const float*)d_in[16];
    const int*   lengths  = (const int*)d_in[17];

    float* out = (float*)d_out;
    const size_t OUT_OFF = (size_t)T_ * B_ * 512;
    float* hn0 = out + OUT_OFF;
    float* hn1 = hn0 + 2 * B_ * H_;

    const size_t PE = (size_t)T_ * B_ * G3;
    const int M = T_ * B_;
    dim3 gg(G3 / 64, M / 64);

    if (ws_size >= 2 * PE * sizeof(float)) {
        float* P0 = (float*)d_ws;
        float* P1 = P0 + PE;
        gemm_bias_nt<float><<<gg, 256, 0, stream>>>(x, w_ih_l0f, b_ih_l0f, P0, M, G3, 256);
        gemm_bias_nt<float><<<gg, 256, 0, stream>>>(x, w_ih_l0b, b_ih_l0b, P1, M, G3, 256);
        gru_scan_reg<float><<<64, 512, 0, stream>>>(P0, P1, w_hh_l0f, w_hh_l0b,
                                                    b_hh_l0f, b_hh_l0b, lengths, out, hn0, 0);
        gemm_bias_nt<float><<<gg, 256, 0, stream>>>(out, w_ih_l1f, b_ih_l1f, P0, M, G3, 512);
        gemm_bias_nt<float><<<gg, 256, 0, stream>>>(out, w_ih_l1b, b_ih_l1b, P1, M, G3, 512);
        gru_scan_reg<float><<<64, 512, 0, stream>>>(P0, P1, w_hh_l1f, w_hh_l1b,
                                                    b_hh_l1f, b_hh_l1b, lengths, out, hn1, 1);
    } else if (ws_size >= 2 * PE * sizeof(__hip_bfloat16)) {
        __hip_bfloat16* P0 = (__hip_bfloat16*)d_ws;
        __hip_bfloat16* P1 = P0 + PE;
        gemm_bias_nt<__hip_bfloat16><<<gg, 256, 0, stream>>>(x, w_ih_l0f, b_ih_l0f, P0, M, G3, 256);
        gemm_bias_nt<__hip_bfloat16><<<gg, 256, 0, stream>>>(x, w_ih_l0b, b_ih_l0b, P1, M, G3, 256);
        gru_scan_reg<__hip_bfloat16><<<64, 512, 0, stream>>>(P0, P1, w_hh_l0f, w_hh_l0b,
                                                             b_hh_l0f, b_hh_l0b, lengths, out, hn0, 0);
        gemm_bias_nt<__hip_bfloat16><<<gg, 256, 0, stream>>>(out, w_ih_l1f, b_ih_l1f, P0, M, G3, 512);
        gemm_bias_nt<__hip_bfloat16><<<gg, 256, 0, stream>>>(out, w_ih_l1b, b_ih_l1b, P1, M, G3, 512);
        gru_scan_reg<__hip_bfloat16><<<64, 512, 0, stream>>>(P0, P1, w_hh_l1f, w_hh_l1b,
                                                             b_hh_l1f, b_hh_l1b, lengths, out, hn1, 1);
    }
}

// Round 3
// 3511.599 us; speedup vs baseline: 12.8128x; 1.0507x over previous
//
#include <hip/hip_runtime.h>
#include <hip/hip_bf16.h>
#include <hip/hip_fp16.h>

#define T_ 1024
#define B_ 32
#define H_ 256
#define G3 768   // 3*H

typedef _Float16 half2_t __attribute__((ext_vector_type(2)));

__device__ __forceinline__ float sigmoidf_(float x) { return 1.f / (1.f + __expf(-x)); }
__device__ __forceinline__ float tanhf_(float x) {
    float e = __expf(2.f * x);
    return (e - 1.f) / (e + 1.f);
}

// Barrier that does NOT drain vmcnt: LDS-ordering only. In-flight global
// prefetch loads / out stores stay outstanding across it; the compiler
// places the vmcnt wait at the value's actual use (end of step).
__device__ __forceinline__ void sync_lds() {
    asm volatile("s_waitcnt lgkmcnt(0)" ::: "memory");
    asm volatile("s_barrier" ::: "memory");
}

__device__ __forceinline__ float fdot2_(unsigned int w, unsigned int h, float acc) {
#if __has_builtin(__builtin_amdgcn_fdot2)
    return __builtin_amdgcn_fdot2(__builtin_bit_cast(half2_t, w),
                                  __builtin_bit_cast(half2_t, h), acc, false);
#else
    half2_t a = __builtin_bit_cast(half2_t, w);
    half2_t b = __builtin_bit_cast(half2_t, h);
    return acc + (float)a[0] * (float)b[0] + (float)a[1] * (float)b[1];
#endif
}

__device__ __forceinline__ unsigned int pack_f16rn(float x, float y) {
    unsigned short ux = __half_as_ushort(__float2half_rn(x));
    unsigned short uy = __half_as_ushort(__float2half_rn(y));
    return (unsigned int)ux | ((unsigned int)uy << 16);
}

// C[M,N] = A[M,K] @ W[N,K]^T + bias[N]
template <typename CT>
__global__ __launch_bounds__(256) void gemm_bias_nt(
    const float* __restrict__ A, const float* __restrict__ W,
    const float* __restrict__ bias, CT* __restrict__ C,
    int M, int N, int K)
{
    __shared__ float As[16][68];
    __shared__ float Ws[16][68];
    const int tid = threadIdx.x;
    const int bm = blockIdx.y * 64;
    const int bn = blockIdx.x * 64;
    const int lr = tid & 63;
    const int lc = tid >> 6;
    const int tx = tid & 15;
    const int ty = tid >> 4;

    const float* Ap = A + (size_t)(bm + lr) * K + lc * 4;
    const float* Wp = W + (size_t)(bn + lr) * K + lc * 4;

    float acc[4][4];
#pragma unroll
    for (int i = 0; i < 4; ++i)
#pragma unroll
        for (int j = 0; j < 4; ++j) acc[i][j] = 0.f;

    for (int k0 = 0; k0 < K; k0 += 16) {
        float4 av = *(const float4*)(Ap + k0);
        float4 wv = *(const float4*)(Wp + k0);
        __syncthreads();
        As[lc * 4 + 0][lr] = av.x; As[lc * 4 + 1][lr] = av.y;
        As[lc * 4 + 2][lr] = av.z; As[lc * 4 + 3][lr] = av.w;
        Ws[lc * 4 + 0][lr] = wv.x; Ws[lc * 4 + 1][lr] = wv.y;
        Ws[lc * 4 + 2][lr] = wv.z; Ws[lc * 4 + 3][lr] = wv.w;
        __syncthreads();
#pragma unroll
        for (int kk = 0; kk < 16; ++kk) {
            float4 a4 = *(const float4*)&As[kk][ty * 4];
            float4 w4 = *(const float4*)&Ws[kk][tx * 4];
            float am[4] = {a4.x, a4.y, a4.z, a4.w};
            float wn[4] = {w4.x, w4.y, w4.z, w4.w};
#pragma unroll
            for (int i = 0; i < 4; ++i)
#pragma unroll
                for (int j = 0; j < 4; ++j) acc[i][j] += am[i] * wn[j];
        }
    }

#pragma unroll
    for (int i = 0; i < 4; ++i) {
        size_t cbase = (size_t)(bm + ty * 4 + i) * N + bn + tx * 4;
#pragma unroll
        for (int j = 0; j < 4; ++j) {
            float v = acc[i][j] + bias[bn + tx * 4 + j];
            C[cbase + j] = (CT)v;
        }
    }
}

// One WG per (batch, direction), 512 threads = (j in 0..255, kh in 0..1).
// W_hh register-resident as packed f16x2. h: fp32 state in thread j's reg,
// broadcast as f16 via 512B LDS. kh=0 keeps its partials in registers; only
// kh=1 round-trips partials through LDS. Barriers are LDS-only (no vmcnt
// drain) so the next-step P prefetch stays in flight across them.
template <typename PT>
__global__ __launch_bounds__(512, 2) void gru_scan_reg(
    const PT* __restrict__ Pf, const PT* __restrict__ Pb,
    const float* __restrict__ Wf, const float* __restrict__ Wb,
    const float* __restrict__ bhf, const float* __restrict__ bhb,
    const int* __restrict__ lengths,
    float* __restrict__ out,   // (T,B,512)
    float* __restrict__ hn,    // [dir][b][j]
    int do_mask)
{
    const int b = blockIdx.x >> 1;
    const int dir = blockIdx.x & 1;
    const PT* P = dir ? Pb : Pf;
    const float* W = dir ? Wb : Wf;
    const float* bh = dir ? bhb : bhf;
    const int len = lengths[b];

    __shared__ unsigned short h16s[H_];   // h as f16 for the matvec
    __shared__ float part[3][H_];         // kh=1 partials only

    const int tid = threadIdx.x;
    const int j = tid & 255;
    const int kh = tid >> 8;

    // ---- load W_hh into registers (one time) ----
    unsigned int wr[64], wz[64], wn[64];
    {
        const float4* r0 = (const float4*)(W + (size_t)j * H_ + kh * 128);
        const float4* r1 = (const float4*)(W + (size_t)(j + 256) * H_ + kh * 128);
        const float4* r2 = (const float4*)(W + (size_t)(j + 512) * H_ + kh * 128);
#pragma unroll
        for (int q = 0; q < 32; ++q) {
            float4 a = r0[q]; wr[2 * q] = pack_f16rn(a.x, a.y); wr[2 * q + 1] = pack_f16rn(a.z, a.w);
            float4 c = r1[q]; wz[2 * q] = pack_f16rn(c.x, c.y); wz[2 * q + 1] = pack_f16rn(c.z, c.w);
            float4 d = r2[q]; wn[2 * q] = pack_f16rn(d.x, d.y); wn[2 * q + 1] = pack_f16rn(d.z, d.w);
        }
    }

    float bh0 = 0.f, bh1 = 0.f, bh2 = 0.f;
    if (tid < H_) { bh0 = bh[j]; bh1 = bh[j + 256]; bh2 = bh[j + 512]; }

    float hreg = 0.f;
    if (tid < H_) h16s[tid] = 0;

    float* outp = out + (size_t)b * 512 + dir * 256;
    float* hnp = hn + (size_t)dir * (B_ * H_) + (size_t)b * H_;

    // incremental row tracking (replaces per-step mul/and chains)
    int crow = dir ? ((len - 1) & (T_ - 1)) : 0;   // row of current step
    int prow = dir ? ((len - 2) & (T_ - 1)) : 1;   // row of next step (prefetch)
    const int rstep = dir ? -1 : 1;
    const PT* Pbase = P + (size_t)b * G3 + j;

    // prologue: P for step 0
    float cir = 0.f, ciz = 0.f, cin = 0.f;
    if (tid < H_) {
        const PT* pp = Pbase + (size_t)crow * (B_ * G3);
        cir = (float)pp[0]; ciz = (float)pp[256]; cin = (float)pp[512];
    }
    sync_lds();

    for (int s = 0; s < T_; ++s) {
        // prefetch next step's input projections (stays in flight across barriers)
        float nir = 0.f, niz = 0.f, nin = 0.f;
        if (s + 1 < T_ && tid < H_) {
            const PT* pp = Pbase + (size_t)prow * (B_ * G3);
            nir = (float)pp[0]; niz = (float)pp[256]; nin = (float)pp[512];
        }

        // ---- matvec from register-resident weights ----
        float ar0 = 0.f, ar1 = 0.f, az0 = 0.f, az1 = 0.f, an0 = 0.f, an1 = 0.f;
        const uint4* hv = ((const uint4*)h16s) + kh * 16;
#pragma unroll
        for (int m = 0; m < 8; ++m) {
            uint4 ua = hv[2 * m];
            uint4 ub = hv[2 * m + 1];
            ar0 = fdot2_(wr[8 * m + 0], ua.x, ar0);
            az0 = fdot2_(wz[8 * m + 0], ua.x, az0);
            an0 = fdot2_(wn[8 * m + 0], ua.x, an0);
            ar1 = fdot2_(wr[8 * m + 1], ua.y, ar1);
            az1 = fdot2_(wz[8 * m + 1], ua.y, az1);
            an1 = fdot2_(wn[8 * m + 1], ua.y, an1);
            ar0 = fdot2_(wr[8 * m + 2], ua.z, ar0);
            az0 = fdot2_(wz[8 * m + 2], ua.z, az0);
            an0 = fdot2_(wn[8 * m + 2], ua.z, an0);
            ar1 = fdot2_(wr[8 * m + 3], ua.w, ar1);
            az1 = fdot2_(wz[8 * m + 3], ua.w, az1);
            an1 = fdot2_(wn[8 * m + 3], ua.w, an1);
            ar0 = fdot2_(wr[8 * m + 4], ub.x, ar0);
            az0 = fdot2_(wz[8 * m + 4], ub.x, az0);
            an0 = fdot2_(wn[8 * m + 4], ub.x, an0);
            ar1 = fdot2_(wr[8 * m + 5], ub.y, ar1);
            az1 = fdot2_(wz[8 * m + 5], ub.y, az1);
            an1 = fdot2_(wn[8 * m + 5], ub.y, an1);
            ar0 = fdot2_(wr[8 * m + 6], ub.z, ar0);
            az0 = fdot2_(wz[8 * m + 6], ub.z, az0);
            an0 = fdot2_(wn[8 * m + 6], ub.z, an0);
            ar1 = fdot2_(wr[8 * m + 7], ub.w, ar1);
            az1 = fdot2_(wz[8 * m + 7], ub.w, az1);
            an1 = fdot2_(wn[8 * m + 7], ub.w, an1);
        }
        const float ar = ar0 + ar1;
        const float az = az0 + az1;
        const float an = an0 + an1;
        if (kh) {                         // wave-uniform branch (waves 4-7)
            part[0][j] = ar;
            part[1][j] = az;
            part[2][j] = an;
        }
        sync_lds();

        if (tid < H_) {                   // waves 0-3: epilogue, own partial in reg
            float gr = ar + part[0][j] + bh0;
            float gz = az + part[1][j] + bh1;
            float gn = an + part[2][j] + bh2;
            float r = sigmoidf_(cir + gr);
            float z = sigmoidf_(ciz + gz);
            float nn = tanhf_(cin + r * gn);
            float hnew = (1.f - z) * nn + z * hreg;
            hreg = hnew;
            h16s[j] = __half_as_ushort(__float2half_rn(hnew));
            float ov = (do_mask && crow >= len) ? 0.f : hnew;
            outp[(size_t)crow * (B_ * 512) + j] = ov;
            if (s == len - 1) hnp[j] = hnew;   // same condition both dirs
        }
        sync_lds();

        cir = nir; ciz = niz; cin = nin;
        crow = (crow + rstep) & (T_ - 1);
        prow = (prow + rstep) & (T_ - 1);
    }
}

extern "C" void kernel_launch(void* const* d_in, const int* in_sizes, int n_in,
                              void* d_out, int out_size, void* d_ws, size_t ws_size,
                              hipStream_t stream)
{
    const float* x        = (const float*)d_in[0];
    const float* w_ih_l0f = (const float*)d_in[1];
    const float* w_hh_l0f = (const float*)d_in[2];
    const float* b_ih_l0f = (const float*)d_in[3];
    const float* b_hh_l0f = (const float*)d_in[4];
    const float* w_ih_l0b = (const float*)d_in[5];
    const float* w_hh_l0b = (const float*)d_in[6];
    const float* b_ih_l0b = (const float*)d_in[7];
    const float* b_hh_l0b = (const float*)d_in[8];
    const float* w_ih_l1f = (const float*)d_in[9];
    const float* w_hh_l1f = (const float*)d_in[10];
    const float* b_ih_l1f = (const float*)d_in[11];
    const float* b_hh_l1f = (const float*)d_in[12];
    const float* w_ih_l1b = (const float*)d_in[13];
    const float* w_hh_l1b = (const float*)d_in[14];
    const float* b_ih_l1b = (const float*)d_in[15];
    const float* b_hh_l1b = (const float*)d_in[16];
    const int*   lengths  = (const int*)d_in[17];

    float* out = (float*)d_out;
    const size_t OUT_OFF = (size_t)T_ * B_ * 512;
    float* hn0 = out + OUT_OFF;
    float* hn1 = hn0 + 2 * B_ * H_;

    const size_t PE = (size_t)T_ * B_ * G3;
    const int M = T_ * B_;
    dim3 gg(G3 / 64, M / 64);

    if (ws_size >= 2 * PE * sizeof(float)) {
        float* P0 = (float*)d_ws;
        float* P1 = P0 + PE;
        gemm_bias_nt<float><<<gg, 256, 0, stream>>>(x, w_ih_l0f, b_ih_l0f, P0, M, G3, 256);
        gemm_bias_nt<float><<<gg, 256, 0, stream>>>(x, w_ih_l0b, b_ih_l0b, P1, M, G3, 256);
        gru_scan_reg<float><<<64, 512, 0, stream>>>(P0, P1, w_hh_l0f, w_hh_l0b,
                                                    b_hh_l0f, b_hh_l0b, lengths, out, hn0, 0);
        gemm_bias_nt<float><<<gg, 256, 0, stream>>>(out, w_ih_l1f, b_ih_l1f, P0, M, G3, 512);
        gemm_bias_nt<float><<<gg, 256, 0, stream>>>(out, w_ih_l1b, b_ih_l1b, P1, M, G3, 512);
        gru_scan_reg<float><<<64, 512, 0, stream>>>(P0, P1, w_hh_l1f, w_hh_l1b,
                                                    b_hh_l1f, b_hh_l1b, lengths, out, hn1, 1);
    } else if (ws_size >= 2 * PE * sizeof(__hip_bfloat16)) {
        __hip_bfloat16* P0 = (__hip_bfloat16*)d_ws;
        __hip_bfloat16* P1 = P0 + PE;
        gemm_bias_nt<__hip_bfloat16><<<gg, 256, 0, stream>>>(x, w_ih_l0f, b_ih_l0f, P0, M, G3, 256);
        gemm_bias_nt<__hip_bfloat16><<<gg, 256, 0, stream>>>(x, w_ih_l0b, b_ih_l0b, P1, M, G3, 256);
        gru_scan_reg<__hip_bfloat16><<<64, 512, 0, stream>>>(P0, P1, w_hh_l0f, w_hh_l0b,
                                                             b_hh_l0f, b_hh_l0b, lengths, out, hn0, 0);
        gemm_bias_nt<__hip_bfloat16><<<gg, 256, 0, stream>>>(out, w_ih_l1f, b_ih_l1f, P0, M, G3, 512);
        gemm_bias_nt<__hip_bfloat16><<<gg, 256, 0, stream>>>(out, w_ih_l1b, b_ih_l1b, P1, M, G3, 512);
        gru_scan_reg<__hip_bfloat16><<<64, 512, 0, stream>>>(P0, P1, w_hh_l1f, w_hh_l1b,
                                                             b_hh_l1f, b_hh_l1b, lengths, out, hn1, 1);
    }
}